// Round 1
// 350.167 us; speedup vs baseline: 1.0527x; 1.0527x over previous
//
#include <hip/hip_runtime.h>
#include <cstdint>
#include <cmath>

// ---------------------------------------------------------------------------
// Vit_Channel_Map: bn=16, C=64, P=16384, DIM=1024, HEADS=8, DH=128
// R(this): GEMM1 + final GEMM moved to gemm8 — 256x256 tile, BK=64, 8 waves
// (512 thr), 128KB LDS double-buffered, 8-phase schedule with counted vmcnt
// (T3+T4), XOR granule swizzle g^=(row&7) on both stage-source and ds_read
// (T2), setprio around MFMA clusters (T5). Unit stagger (per wave, in-order
// vmem queue), tile t staging tile t+1 into the other buffer:
//   ph1 needs A-U0,U2 + B-U4..U7 of t (landed: prev ph4 vmcnt(2))
//   ph3 needs A-U1,U3 of t          (landed: ph2 vmcnt(4))
//   issue order: ph1: B0,B1 | ph2: B2,B3 + vmcnt(4) | ph3: A0,A2 |
//                ph4: A1,A3 + vmcnt(2)
// Steady-state queue never drains to 0. Prologue stages tile0 as
// [A0,A2,B0..B3,A1,A3] + vmcnt(2) so tile 0 follows the steady schedule.
// prep_fused = 4x cvt_bf16 + wqm2 in one dispatch (fewer launch gaps).
// GEMM-v (K=1024 splitK=8) stays on gemm_db (shape too small for 256^2).
// ---------------------------------------------------------------------------

typedef __attribute__((ext_vector_type(8))) short short8;
typedef __attribute__((ext_vector_type(4))) float f32x4;

#define DIMD 1024
#define NCH  64
#define NHEAD 8
#define DHEAD 128

typedef __attribute__((address_space(1))) unsigned int gu32;
typedef __attribute__((address_space(3))) unsigned int lu32;

__device__ __forceinline__ void gload_lds16(const void* g, void* l) {
  __builtin_amdgcn_global_load_lds((gu32*)g, (lu32*)l, 16, 0, 0);
}

__device__ __forceinline__ unsigned short f2bf(float f) {
  union { float f; unsigned u; } a; a.f = f;
  unsigned u = a.u;
  unsigned r = (u + 0x7fffu + ((u >> 16) & 1u)) >> 16;
  return (unsigned short)r;
}
__device__ __forceinline__ float bf2f(unsigned short h) {
  union { unsigned u; float f; } a; a.u = ((unsigned)h) << 16; return a.f;
}

// ---- elementwise fp32 -> bf16, 8 elems/thread ----
__device__ __forceinline__ void cvt8_body(const float* __restrict__ in,
                                          unsigned short* __restrict__ out, int i) {
  const float4* p = (const float4*)in + (size_t)i * 2;
  float4 f0 = p[0], f1 = p[1];
  uint4 u;
  u.x = (unsigned)f2bf(f0.x) | ((unsigned)f2bf(f0.y) << 16);
  u.y = (unsigned)f2bf(f0.z) | ((unsigned)f2bf(f0.w) << 16);
  u.z = (unsigned)f2bf(f1.x) | ((unsigned)f2bf(f1.y) << 16);
  u.w = (unsigned)f2bf(f1.z) | ((unsigned)f2bf(f1.w) << 16);
  ((uint4*)out)[i] = u;
}

__global__ __launch_bounds__(256) void cvt_bf16_kernel(
    const float* __restrict__ in, unsigned short* __restrict__ out, int n8) {
  int i = blockIdx.x * 256 + threadIdx.x;
  if (i >= n8) return;
  cvt8_body(in, out, i);
}

// ---- fused prep: cvt x/We/Wo/Wv + wqm in ONE dispatch ----
// blocks [0,8192) x ; [8192,16384) We ; [16384,24576) Wo ; [24576,25088) Wv ;
// [25088,25152) wqm2
__global__ __launch_bounds__(256) void prep_fused(
    const float* __restrict__ x,  unsigned short* __restrict__ x_bf,
    const float* __restrict__ We, unsigned short* __restrict__ We_bf,
    const float* __restrict__ Wo, unsigned short* __restrict__ Wo_bf,
    const float* __restrict__ Wv, unsigned short* __restrict__ Wv_bf,
    const float* __restrict__ Wq, float* __restrict__ wqm) {
  int b = blockIdx.x;
  if (b < 8192) {
    cvt8_body(x, x_bf, b * 256 + threadIdx.x);
  } else if (b < 16384) {
    cvt8_body(We, We_bf, (b - 8192) * 256 + threadIdx.x);
  } else if (b < 24576) {
    cvt8_body(Wo, Wo_bf, (b - 16384) * 256 + threadIdx.x);
  } else if (b < 25088) {
    cvt8_body(Wv, Wv_bf, (b - 24576) * 256 + threadIdx.x);
  } else {
    int bb = b - 25088;
    int h = bb >> 3, dbase = (bb & 7) * 128;
    int d = threadIdx.x & 127, eh = threadIdx.x >> 7;
    const float* p = Wq + ((size_t)(h * DHEAD + eh * 64)) * DIMD + dbase + d;
    float s = 0.f;
    #pragma unroll 8
    for (int e = 0; e < 64; ++e) s += p[(size_t)e * DIMD];
    __shared__ float red[2][128];
    red[eh][d] = s;
    __syncthreads();
    if (eh == 0)
      wqm[h * DIMD + dbase + d] = (red[0][d] + red[1][d]) * (1.0f / DHEAD);
  }
}

// ---- wqm[h][d] = mean_e Wq[h*128+e][d] ; 64 blocks (tier B path) ----
__global__ __launch_bounds__(256) void wqm2_kernel(
    const float* __restrict__ Wq, float* __restrict__ wqm) {
  int h = blockIdx.x >> 3, dbase = (blockIdx.x & 7) * 128;
  int d = threadIdx.x & 127, eh = threadIdx.x >> 7;
  const float* p = Wq + ((size_t)(h * DHEAD + eh * 64)) * DIMD + dbase + d;
  float s = 0.f;
  #pragma unroll 8
  for (int e = 0; e < 64; ++e) s += p[(size_t)e * DIMD];
  __shared__ float red[2][128];
  red[eh][d] = s;
  __syncthreads();
  if (eh == 0)
    wqm[h * DIMD + dbase + d] = (red[0][d] + red[1][d]) * (1.0f / DHEAD);
}

// ---- q = xe @ wqm^T ; k = sigmoid(q @ Wk^T). Grid (16 batch, 8 head) ----
__global__ __launch_bounds__(256) void qk2_kernel(
    const unsigned short* __restrict__ xe, const float* __restrict__ wqm,
    const float* __restrict__ Wk, float* __restrict__ kout) {
  int b = blockIdx.x, h = blockIdx.y;
  int c = threadIdx.x & 63, dq = threadIdx.x >> 6;
  __shared__ float red[64][4];
  __shared__ float qs[64];
  const uint4* xr = (const uint4*)(xe + ((size_t)(b * NCH + c)) * DIMD + dq * 256);
  const float* wr = wqm + h * DIMD + dq * 256;
  float s = 0.f;
  #pragma unroll 4
  for (int i = 0; i < 32; ++i) {
    uint4 v = xr[i];
    s += bf2f((unsigned short)(v.x & 0xffff)) * wr[i * 8 + 0];
    s += bf2f((unsigned short)(v.x >> 16))    * wr[i * 8 + 1];
    s += bf2f((unsigned short)(v.y & 0xffff)) * wr[i * 8 + 2];
    s += bf2f((unsigned short)(v.y >> 16))    * wr[i * 8 + 3];
    s += bf2f((unsigned short)(v.z & 0xffff)) * wr[i * 8 + 4];
    s += bf2f((unsigned short)(v.z >> 16))    * wr[i * 8 + 5];
    s += bf2f((unsigned short)(v.w & 0xffff)) * wr[i * 8 + 6];
    s += bf2f((unsigned short)(v.w >> 16))    * wr[i * 8 + 7];
  }
  red[c][dq] = s;
  __syncthreads();
  if (dq == 0) qs[c] = red[c][0] + red[c][1] + red[c][2] + red[c][3];
  __syncthreads();
  int f = c;
  float s2 = 0.f;
  #pragma unroll
  for (int i = 0; i < 16; ++i) {
    int cc = dq * 16 + i;
    s2 += qs[cc] * Wk[f * NCH + cc];
  }
  red[f][dq] = s2;
  __syncthreads();
  if (dq == 0) {
    float q = red[f][0] + red[f][1] + red[f][2] + red[f][3];
    kout[(b * NHEAD + h) * NCH + f] = 1.f / (1.f + expf(-q));
  }
}

// ===========================================================================
// gemm8: 256x256-tile, BK=64, 8-wave 8-phase bf16 GEMM, C = A @ B^T.
// A:[M][K] bf16, B:[N][K] bf16.
// MODE 3: fp32 partial store to C[z][M][N] (split-K); MODE 2: C = acc + bias.
// LAYOUT 1 (splitK=16, 256 blocks): kz=(bid&7)|(((bid>>3)&1)<<3);
//   r=bid>>4: n0=(r&3)*256, m0=(r>>2)*256. (same-kz blocks share XCD -> L2)
// LAYOUT 2 (no split, 256 blocks): nlo=bid&7; r=bid>>3: m0=(r&3)*256,
//   n0=(nlo+8*(r>>2))*256. (4 blocks sharing a Wo chunk share an XCD)
// ===========================================================================

#define BARR asm volatile("s_barrier" ::: "memory")
#define VMW(n) asm volatile("s_waitcnt vmcnt(" #n ")" ::: "memory")
#define ENDPH do { \
  asm volatile("s_waitcnt lgkmcnt(0)" ::: "memory"); \
  __builtin_amdgcn_sched_barrier(0); \
  BARR; } while (0)

// stage unit u (64 rows x 64 cols = 8KB, one gload_lds16/thread) of tile at
// element-k offset kk into buffer bb. Source column is pre-swizzled so the
// linear global_load_lds dest yields LDS granule g holding global granule
// g ^ (row&7).
#define SA(bb, kk, u) gload_lds16(gA + (size_t)(u) * 64 * K + (kk), \
                                  lA0 + (bb) * 16384 + (u) * 4096)
#define SB(bb, kk, u) gload_lds16(gB + (size_t)(u) * 64 * K + (kk), \
                                  lB0 + (bb) * 16384 + (u) * 4096)

// one phase: ds_read fragments (swizzled) -> stage issues -> barrier ->
// setprio(1) 16 MFMA setprio(0) -> lgkmcnt(0) -> barrier
#define PH(QM, QN, LOADA, STG) do { \
  if (LOADA) { \
    const unsigned short* ap = &As[buf][wm * 128 + (QM) * 64 + rl][0]; \
    _Pragma("unroll") \
    for (int i = 0; i < 4; ++i) { \
      af0[i] = *(const short8*)(ap + i * 1024 + ((q ^ swz) << 3)); \
      af1[i] = *(const short8*)(ap + i * 1024 + (((4 | q) ^ swz) << 3)); \
    } \
  } \
  const unsigned short* bp = &Bs[buf][wn * 64 + (QN) * 32 + rl][0]; \
  short8 b00 = *(const short8*)(bp + ((q ^ swz) << 3)); \
  short8 b01 = *(const short8*)(bp + 1024 + ((q ^ swz) << 3)); \
  short8 b10 = *(const short8*)(bp + (((4 | q) ^ swz) << 3)); \
  short8 b11 = *(const short8*)(bp + 1024 + (((4 | q) ^ swz) << 3)); \
  STG; \
  BARR; \
  __builtin_amdgcn_s_setprio(1); \
  _Pragma("unroll") \
  for (int i = 0; i < 4; ++i) { \
    acc[(QM)*4+i][(QN)*2+0] = __builtin_amdgcn_mfma_f32_16x16x32_bf16(af0[i], b00, acc[(QM)*4+i][(QN)*2+0], 0, 0, 0); \
    acc[(QM)*4+i][(QN)*2+0] = __builtin_amdgcn_mfma_f32_16x16x32_bf16(af1[i], b10, acc[(QM)*4+i][(QN)*2+0], 0, 0, 0); \
    acc[(QM)*4+i][(QN)*2+1] = __builtin_amdgcn_mfma_f32_16x16x32_bf16(af0[i], b01, acc[(QM)*4+i][(QN)*2+1], 0, 0, 0); \
    acc[(QM)*4+i][(QN)*2+1] = __builtin_amdgcn_mfma_f32_16x16x32_bf16(af1[i], b11, acc[(QM)*4+i][(QN)*2+1], 0, 0, 0); \
  } \
  __builtin_amdgcn_s_setprio(0); \
  ENDPH; \
} while (0)

template<int MODE, int LAYOUT>
__global__ __launch_bounds__(512, 2) void gemm8(
    const unsigned short* __restrict__ A, const unsigned short* __restrict__ Bg,
    float* __restrict__ C, const float* __restrict__ bias,
    int M, int N, int K, int Ksub)
{
  __shared__ __align__(16) unsigned short As[2][256][64];
  __shared__ __align__(16) unsigned short Bs[2][256][64];

  const int bid = blockIdx.x;
  int m0, n0, kz;
  if (LAYOUT == 1) {
    kz = (bid & 7) | (((bid >> 3) & 1) << 3);
    int r = bid >> 4; n0 = (r & 3) * 256; m0 = (r >> 2) * 256;
  } else {
    int nlo = bid & 7; int r = bid >> 3;
    m0 = (r & 3) * 256; n0 = (nlo + 8 * (r >> 2)) * 256; kz = 0;
  }
  const int kbeg = kz * Ksub;
  const int NT = Ksub >> 6;

  const int tid  = threadIdx.x;
  const int lane = tid & 63, wave = tid >> 6;
  const int wm = wave >> 2, wn = wave & 3;       // 2 x 4 wave grid
  const int q = lane >> 4, rl = lane & 15;
  const int swz = rl & 7;

  // per-thread staging bases: thread covers row (wave*8 + lane>>3) of each
  // 64-row unit, source granule = (lane&7) ^ (row&7)  [lane-only]
  const int srow = wave * 8 + (lane >> 3);
  const int kswz = ((lane & 7) ^ (lane >> 3)) << 3;
  const unsigned short* gA = A  + (size_t)(m0 + srow) * K + kbeg + kswz;
  const unsigned short* gB = Bg + (size_t)(n0 + srow) * K + kbeg + kswz;
  unsigned short* lA0 = &As[0][0][0] + wave * 512;
  unsigned short* lB0 = &Bs[0][0][0] + wave * 512;

  f32x4 acc[8][4] = {};
  short8 af0[4], af1[4];

  // prologue: stage tile 0 in order [A0,A2,B0,B1,B2,B3,A1,A3]; vmcnt(2)
  // leaves exactly A1,A3 outstanding = steady-state entry condition.
  SA(0, 0, 0); SA(0, 0, 2);
  SB(0, 0, 0); SB(0, 0, 1); SB(0, 0, 2); SB(0, 0, 3);
  SA(0, 0, 1); SA(0, 0, 3);
  VMW(2);
  BARR;

  for (int t = 0; t < NT; ++t) {
    const int buf = t & 1;
    const int nb = buf ^ 1;
    const bool s = (t + 1) < NT;
    const size_t kn = (size_t)(t + 1) * 64;

    PH(0, 0, true,  if (s) { SB(nb, kn, 0); SB(nb, kn, 1); });
    PH(0, 1, false, if (s) { SB(nb, kn, 2); SB(nb, kn, 3); VMW(4); } else VMW(0));
    PH(1, 0, true,  if (s) { SA(nb, kn, 0); SA(nb, kn, 2); });
    PH(1, 1, false, if (s) { SA(nb, kn, 1); SA(nb, kn, 3); VMW(2); });
  }

  const size_t zoff = (MODE == 3) ? (size_t)kz * (size_t)M * (size_t)N : 0;
  #pragma unroll
  for (int mi = 0; mi < 8; ++mi) {
    #pragma unroll
    for (int nj = 0; nj < 4; ++nj) {
      #pragma unroll
      for (int r = 0; r < 4; ++r) {
        int row = m0 + wm * 128 + mi * 16 + q * 4 + r;
        int col = n0 + wn * 64 + nj * 16 + rl;
        if (MODE == 3) {
          C[zoff + (size_t)row * N + col] = acc[mi][nj][r];
        } else {
          C[(size_t)row * N + col] = acc[mi][nj][r] + bias[col];
        }
      }
    }
  }
}

// ---- double-buffered bf16 GEMM (128^2, BK=32) — kept for GEMM-v / tier B ----
template<int MODE, int LAYOUT>
__global__ __launch_bounds__(256) void gemm_db(
    const unsigned short* __restrict__ A, const unsigned short* __restrict__ B,
    float* __restrict__ C, const float* __restrict__ bias,
    int M, int N, int K, int Ksub)
{
  __shared__ __align__(16) unsigned short As[2][128][32];
  __shared__ __align__(16) unsigned short Bs[2][128][32];

  const int bid = blockIdx.x;
  int m0, n0, kz;
  if (LAYOUT == 0) {
    kz = bid & 7; int r = bid >> 3; n0 = (r & 7) * 128; m0 = (r >> 3) * 128;
  } else if (LAYOUT == 1) {
    kz = (bid & 7) | (((bid >> 3) & 1) << 3);
    int r = bid >> 4; n0 = (r & 7) * 128; m0 = (r >> 3) * 128;
  } else {
    int nlo = bid & 7, nhi = bid >> 6;
    m0 = ((bid >> 3) & 7) * 128; n0 = (nlo + 8 * nhi) * 128; kz = 0;
  }

  const int tid  = threadIdx.x;
  const int lane = tid & 63, wave = tid >> 6;
  const int kbeg = kz * Ksub;
  const int lrow = lane >> 2;
  const int lcol = (lane & 3) * 8;
  const int q = lane >> 4, rl = lane & 15;
  const int wr = (wave >> 1) * 64, wc = (wave & 1) * 64;

  const unsigned short* ga = A + (size_t)(m0 + wave * 32 + lrow) * K + kbeg + lcol;
  const unsigned short* gb = B + (size_t)(n0 + wave * 32 + lrow) * K + kbeg + lcol;

  f32x4 acc[4][4] = {};

  gload_lds16(ga,                  &As[0][wave * 32][0]);
  gload_lds16(ga + (size_t)16 * K, &As[0][wave * 32 + 16][0]);
  gload_lds16(gb,                  &Bs[0][wave * 32][0]);
  gload_lds16(gb + (size_t)16 * K, &Bs[0][wave * 32 + 16][0]);
  ga += 32; gb += 32;

  int p = 0;
  for (int k0 = 0; k0 < Ksub; k0 += 32) {
    __syncthreads();
    if (k0 + 32 < Ksub) {
      gload_lds16(ga,                  &As[p ^ 1][wave * 32][0]);
      gload_lds16(ga + (size_t)16 * K, &As[p ^ 1][wave * 32 + 16][0]);
      gload_lds16(gb,                  &Bs[p ^ 1][wave * 32][0]);
      gload_lds16(gb + (size_t)16 * K, &Bs[p ^ 1][wave * 32 + 16][0]);
      ga += 32; gb += 32;
    }

    short8 af[4], bf[4];
    #pragma unroll
    for (int i = 0; i < 4; ++i)
      af[i] = *(const short8*)&As[p][wr + i * 16 + rl][q * 8];
    #pragma unroll
    for (int j = 0; j < 4; ++j)
      bf[j] = *(const short8*)&Bs[p][wc + j * 16 + rl][q * 8];
    #pragma unroll
    for (int i = 0; i < 4; ++i)
      #pragma unroll
      for (int j = 0; j < 4; ++j)
        acc[i][j] = __builtin_amdgcn_mfma_f32_16x16x32_bf16(af[i], bf[j], acc[i][j], 0, 0, 0);

    p ^= 1;
  }

  const size_t zoff = (MODE == 3) ? (size_t)kz * (size_t)M * (size_t)N : 0;
  #pragma unroll
  for (int i = 0; i < 4; ++i) {
    #pragma unroll
    for (int j = 0; j < 4; ++j) {
      #pragma unroll
      for (int r = 0; r < 4; ++r) {
        int row = m0 + wr + i * 16 + q * 4 + r;
        int col = n0 + wc + j * 16 + rl;
        if (MODE == 3) {
          C[zoff + (size_t)row * N + col] = acc[i][j][r];
        } else {
          C[(size_t)row * N + col] = acc[i][j][r] + bias[col];
        }
      }
    }
  }
}

// ---- reduce NS splitK partials + be + pos -> bf16 xe ----
template<int NS>
__global__ __launch_bounds__(256) void reduce1_kernel(
    const float* __restrict__ part, const float* __restrict__ be,
    const float* __restrict__ pos, unsigned short* __restrict__ xe) {
  int i = blockIdx.x * 256 + threadIdx.x;
  size_t base = (size_t)i * 4;
  int row = i >> 8, col = (i & 255) * 4;
  float4 s = {0.f, 0.f, 0.f, 0.f};
  #pragma unroll
  for (int sk = 0; sk < NS; ++sk) {
    float4 p = *(const float4*)(part + (size_t)sk * (DIMD * DIMD) + base);
    s.x += p.x; s.y += p.y; s.z += p.z; s.w += p.w;
  }
  float4 bv = *(const float4*)(be + col);
  float4 pv = *(const float4*)(pos + (size_t)(row & 63) * DIMD + col);
  uint2 u;
  u.x = (unsigned)f2bf(s.x + bv.x + pv.x) | ((unsigned)f2bf(s.y + bv.y + pv.y) << 16);
  u.y = (unsigned)f2bf(s.z + bv.z + pv.z) | ((unsigned)f2bf(s.w + bv.w + pv.w) << 16);
  *(uint2*)(xe + base) = u;
}

// ---- reduce NS splitK partials * k-scale -> bf16 t ----
template<int NS>
__global__ __launch_bounds__(256) void reduce2_kernel(
    const float* __restrict__ part, const float* __restrict__ kv,
    unsigned short* __restrict__ t) {
  int i = blockIdx.x * 256 + threadIdx.x;
  size_t base = (size_t)i * 4;
  int row = i >> 8, col = (i & 255) * 4;
  float4 s = {0.f, 0.f, 0.f, 0.f};
  #pragma unroll
  for (int sk = 0; sk < NS; ++sk) {
    float4 p = *(const float4*)(part + (size_t)sk * (DIMD * DIMD) + base);
    s.x += p.x; s.y += p.y; s.z += p.z; s.w += p.w;
  }
  float sc = kv[((row >> 6) * NHEAD + (col >> 7)) * NCH + (row & 63)];
  uint2 u;
  u.x = (unsigned)f2bf(s.x * sc) | ((unsigned)f2bf(s.y * sc) << 16);
  u.y = (unsigned)f2bf(s.z * sc) | ((unsigned)f2bf(s.w * sc) << 16);
  *(uint2*)(t + base) = u;
}

// ===========================================================================
// Tier C fallback (round-1, proven): fp32-staged MFMA GEMM with fused cvt
// ===========================================================================
template<int MODE, bool ABF16, int BM, int BN>
__global__ __launch_bounds__(256) void gemm_bt(
    const void* __restrict__ Ap, const float* __restrict__ B,
    void* __restrict__ C, const float* __restrict__ bias,
    const float* __restrict__ posp, const float* __restrict__ ksc,
    int M, int N, int K)
{
  constexpr int BK = 32;
  constexpr int LDR = BK + 8;
  __shared__ __align__(16) unsigned short As[BM][LDR];
  __shared__ __align__(16) unsigned short Bs[BN][LDR];

  const int tid = threadIdx.x;
  const int m0 = blockIdx.y * BM;
  const int n0 = blockIdx.x * BN;
  constexpr int EA = BM * BK / 256;
  constexpr int EB = BN * BK / 256;
  constexpr int MI = BM / 32;
  constexpr int NI = BN / 32;
  const int lane = tid & 63, wave = tid >> 6;
  const int wr = (wave >> 1) * (BM / 2);
  const int wc = (wave & 1) * (BN / 2);
  const int q = lane >> 4, rl = lane & 15;

  f32x4 acc[MI][NI] = {};

  for (int k0 = 0; k0 < K; k0 += BK) {
    {
      constexpr int CPR = BK / EA;
      int row = tid / CPR;
      int cs  = (tid % CPR) * EA;
      if (ABF16) {
        const unsigned short* a = (const unsigned short*)Ap + (size_t)(m0 + row) * K + k0 + cs;
        #pragma unroll
        for (int v = 0; v < EA / 8; ++v)
          *(uint4*)&As[row][cs + v * 8] = *(const uint4*)(a + v * 8);
      } else {
        const float* a = (const float*)Ap + (size_t)(m0 + row) * K + k0 + cs;
        #pragma unroll
        for (int v = 0; v < EA / 8; ++v) {
          float4 f0 = *(const float4*)(a + v * 8);
          float4 f1 = *(const float4*)(a + v * 8 + 4);
          uint4 u;
          u.x = (unsigned)f2bf(f0.x) | ((unsigned)f2bf(f0.y) << 16);
          u.y = (unsigned)f2bf(f0.z) | ((unsigned)f2bf(f0.w) << 16);
          u.z = (unsigned)f2bf(f1.x) | ((unsigned)f2bf(f1.y) << 16);
          u.w = (unsigned)f2bf(f1.z) | ((unsigned)f2bf(f1.w) << 16);
          *(uint4*)&As[row][cs + v * 8] = u;
        }
      }
    }
    {
      constexpr int CPR = BK / EB;
      int row = tid / CPR;
      int cs  = (tid % CPR) * EB;
      const float* b = B + (size_t)(n0 + row) * K + k0 + cs;
      #pragma unroll
      for (int v = 0; v < EB / 8; ++v) {
        float4 f0 = *(const float4*)(b + v * 8);
        float4 f1 = *(const float4*)(b + v * 8 + 4);
        uint4 u;
        u.x = (unsigned)f2bf(f0.x) | ((unsigned)f2bf(f0.y) << 16);
        u.y = (unsigned)f2bf(f0.z) | ((unsigned)f2bf(f0.w) << 16);
        u.z = (unsigned)f2bf(f1.x) | ((unsigned)f2bf(f1.y) << 16);
        u.w = (unsigned)f2bf(f1.z) | ((unsigned)f2bf(f1.w) << 16);
        *(uint4*)&Bs[row][cs + v * 8] = u;
      }
    }
    __syncthreads();

    short8 af[MI], bf[NI];
    #pragma unroll
    for (int i = 0; i < MI; ++i)
      af[i] = *(const short8*)&As[wr + i * 16 + rl][q * 8];
    #pragma unroll
    for (int j = 0; j < NI; ++j)
      bf[j] = *(const short8*)&Bs[wc + j * 16 + rl][q * 8];
    #pragma unroll
    for (int i = 0; i < MI; ++i)
      #pragma unroll
      for (int j = 0; j < NI; ++j)
        acc[i][j] = __builtin_amdgcn_mfma_f32_16x16x32_bf16(af[i], bf[j], acc[i][j], 0, 0, 0);

    __syncthreads();
  }

  #pragma unroll
  for (int i = 0; i < MI; ++i) {
    #pragma unroll
    for (int j = 0; j < NI; ++j) {
      #pragma unroll
      for (int r = 0; r < 4; ++r) {
        int row = m0 + wr + i * 16 + q * 4 + r;
        int col = n0 + wc + j * 16 + rl;
        float v = acc[i][j][r];
        if (MODE == 0) {
          v += bias[col] + posp[(size_t)(row & 63) * DIMD + col];
          ((unsigned short*)C)[(size_t)row * N + col] = f2bf(v);
        } else if (MODE == 1) {
          v *= ksc[((row >> 6) * NHEAD + (col >> 7)) * NCH + (row & 63)];
          ((unsigned short*)C)[(size_t)row * N + col] = f2bf(v);
        } else {
          ((float*)C)[(size_t)row * N + col] = v + bias[col];
        }
      }
    }
  }
}

// ---- legacy small kernels used by tier C ----
__global__ void wqm_kernel(const float* __restrict__ Wq, float* __restrict__ wqm) {
  int h = blockIdx.x;
  for (int d = threadIdx.x; d < DIMD; d += 256) {
    float s = 0.f;
    const float* p = Wq + (size_t)h * DHEAD * DIMD + d;
    #pragma unroll 4
    for (int e = 0; e < DHEAD; ++e) s += p[(size_t)e * DIMD];
    wqm[h * DIMD + d] = s * (1.0f / DHEAD);
  }
}
__global__ void qk_kernel(const unsigned short* __restrict__ xe,
                          const float* __restrict__ wqm,
                          const float* __restrict__ Wk,
                          float* __restrict__ kout) {
  int b = blockIdx.x;
  __shared__ float qs[NHEAD][NCH];
  for (int t = threadIdx.x; t < NHEAD * NCH; t += 256) {
    int h = t >> 6, c = t & 63;
    const unsigned short* xr = xe + (size_t)(b * NCH + c) * DIMD;
    const float* wr = wqm + h * DIMD;
    float s = 0.f;
    #pragma unroll 8
    for (int d = 0; d < DIMD; ++d) s += bf2f(xr[d]) * wr[d];
    qs[h][c] = s;
  }
  __syncthreads();
  for (int t = threadIdx.x; t < NHEAD * NCH; t += 256) {
    int h = t >> 6, f = t & 63;
    float s = 0.f;
    #pragma unroll
    for (int c = 0; c < NCH; ++c) s += qs[h][c] * Wk[f * NCH + c];
    kout[b * (NHEAD * NCH) + h * NCH + f] = 1.f / (1.f + expf(-s));
  }
}

extern "C" void kernel_launch(void* const* d_in, const int* in_sizes, int n_in,
                              void* d_out, int out_size, void* d_ws, size_t ws_size,
                              hipStream_t stream) {
  const float* x   = (const float*)d_in[0];   // [1024][16384]
  const float* We  = (const float*)d_in[1];   // [1024][16384]
  const float* be  = (const float*)d_in[2];   // [1024]
  const float* pos = (const float*)d_in[3];   // [64][1024]
  const float* Wq  = (const float*)d_in[4];   // [1024][1024]
  const float* Wk  = (const float*)d_in[5];   // [64][64]
  const float* Wv  = (const float*)d_in[6];   // [1024][1024]
  const float* Wo  = (const float*)d_in[7];   // [16384][1024]
  const float* bo  = (const float*)d_in[8];   // [16384]
  float* out = (float*)d_out;                 // [1024][16384] fp32

  const size_t MB = 1u << 20;
  const size_t WS16 = 102 * MB + 64 * 1024;   // tier A
  const size_t WS8  = 70 * MB + 64 * 1024;    // tier B

  if (ws_size >= WS16) {
    char* ws = (char*)d_ws;
    unsigned short* We_bf = (unsigned short*)(ws + 0);           // 32 MB
    unsigned short* Wo_bf = (unsigned short*)(ws + 32 * MB);     // 32 MB
    unsigned short* x_bf  = (unsigned short*)(ws + 64 * MB);     // 32 MB
    unsigned short* Wv_bf = (unsigned short*)(ws + 96 * MB);     // 2 MB
    unsigned short* xe    = (unsigned short*)(ws + 98 * MB);     // 2 MB
    unsigned short* t     = (unsigned short*)(ws + 100 * MB);    // 2 MB
    float* wqm = (float*)(ws + 102 * MB);                        // 32 KB
    float* kv  = (float*)(ws + 102 * MB + 32 * 1024);            // 32 KB

    float* part1 = (float*)d_out;   // [16][1024][1024] = 64 MB
    float* part2 = (float*)d_out;   // [8][1024][1024]  = 32 MB

    prep_fused<<<dim3(25152), 256, 0, stream>>>(
        x, x_bf, We, We_bf, Wo, Wo_bf, Wv, Wv_bf, Wq, wqm);

    // GEMM1: x @ We^T, splitK=16, 256^2 tiles, 8-phase
    gemm8<3, 1><<<dim3(256), 512, 0, stream>>>(
        x_bf, We_bf, part1, nullptr, 1024, 1024, 16384, 1024);
    reduce1_kernel<16><<<dim3(1024), 256, 0, stream>>>(part1, be, pos, xe);

    qk2_kernel<<<dim3(16, 8), 256, 0, stream>>>(xe, wqm, Wk, kv);

    // GEMM-v: xe @ Wv^T, splitK=8 (small K, keep 128^2 structure)
    gemm_db<3, 0><<<dim3(512), 256, 0, stream>>>(
        xe, Wv_bf, part2, nullptr, 1024, 1024, 1024, 128);
    reduce2_kernel<8><<<dim3(1024), 256, 0, stream>>>(part2, kv, t);

    // final: t @ Wo^T + bo -> out, 256^2 tiles, 8-phase, XCD-pinned Wo chunks
    gemm8<2, 2><<<dim3(256), 512, 0, stream>>>(
        t, Wo_bf, out, bo, 1024, 16384, 1024, 1024);
  } else if (ws_size >= WS8) {
    char* ws = (char*)d_ws;
    unsigned short* We_bf = (unsigned short*)(ws + 0);
    unsigned short* Wo_bf = (unsigned short*)(ws + 32 * MB);
    unsigned short* Wv_bf = (unsigned short*)(ws + 64 * MB);
    unsigned short* xe    = (unsigned short*)(ws + 66 * MB);
    unsigned short* t     = (unsigned short*)(ws + 68 * MB);
    float* wqm = (float*)(ws + 70 * MB);
    float* kv  = (float*)(ws + 70 * MB + 32 * 1024);

    char* ob = (char*)d_out;
    unsigned short* x_bf  = (unsigned short*)(ob + 0);
    float* part1 = (float*)(ob + 32 * MB);   // [8][1024][1024] 32 MB
    float* part2 = (float*)(ob + 0);         // [8][1024][1024] 32 MB

    cvt_bf16_kernel<<<dim3(8192), 256, 0, stream>>>(x,  x_bf,  16777216 / 8);
    cvt_bf16_kernel<<<dim3(8192), 256, 0, stream>>>(We, We_bf, 16777216 / 8);
    cvt_bf16_kernel<<<dim3(512),  256, 0, stream>>>(Wv, Wv_bf, 1048576 / 8);
    cvt_bf16_kernel<<<dim3(8192), 256, 0, stream>>>(Wo, Wo_bf, 16777216 / 8);
    wqm2_kernel<<<dim3(64), 256, 0, stream>>>(Wq, wqm);

    gemm_db<3, 0><<<dim3(512), 256, 0, stream>>>(
        x_bf, We_bf, part1, nullptr, 1024, 1024, 16384, 2048);
    reduce1_kernel<8><<<dim3(1024), 256, 0, stream>>>(part1, be, pos, xe);

    qk2_kernel<<<dim3(16, 8), 256, 0, stream>>>(xe, wqm, Wk, kv);

    gemm_db<3, 0><<<dim3(512), 256, 0, stream>>>(
        xe, Wv_bf, part2, nullptr, 1024, 1024, 1024, 128);
    reduce2_kernel<8><<<dim3(1024), 256, 0, stream>>>(part2, kv, t);

    gemm_db<2, 2><<<dim3(1024), 256, 0, stream>>>(
        t, Wo_bf, out, bo, 1024, 16384, 1024, 1024);
  } else {
    char* ws = (char*)d_ws;
    unsigned short* xe = (unsigned short*)ws;
    unsigned short* t  = (unsigned short*)(ws + (2u << 20));
    float* wqm = (float*)(ws + (4u << 20));
    float* kv  = (float*)(ws + (4u << 20) + (32u << 10));

    wqm_kernel<<<dim3(NHEAD), 256, 0, stream>>>(Wq, wqm);
    gemm_bt<0, false, 64, 64><<<dim3(16, 16), 256, 0, stream>>>(
        x, We, xe, be, pos, nullptr, 1024, 1024, 16384);
    qk_kernel<<<dim3(16), 256, 0, stream>>>(xe, wqm, Wk, kv);
    gemm_bt<1, true, 64, 64><<<dim3(16, 16), 256, 0, stream>>>(
        xe, Wv, t, nullptr, nullptr, kv, 1024, 1024, 1024);
    gemm_bt<2, true, 128, 128><<<dim3(128, 8), 256, 0, stream>>>(
        t, Wo, out, bo, nullptr, nullptr, 1024, 16384, 1024);
  }
}